// Round 1
// baseline (562.949 us; speedup 1.0000x reference)
//
#include <hip/hip_runtime.h>
#include <math.h>

#define N_NODES 100000
#define F_IN    100
#define HIDDEN  16
#define N_CLASS 18

// ---- edge dtype detector: int64 little-endian (values < 2^31) has all-zero odd int32 words
__global__ void k_detect(const int* __restrict__ ei, int* __restrict__ flag) {
    int z = 1;
    for (int i = 0; i < 16; ++i) {
        if (ei[2 * i + 1] != 0) z = 0;
    }
    *flag = z;  // 1 => int64 layout, 0 => int32 layout
}

__device__ __forceinline__ int edge_at(const int* __restrict__ ei, long long idx, int is64) {
    return is64 ? ei[2 * idx] : ei[idx];
}

// ---- degree accumulation: deg[dst] += 1 (self-loop +1 folded into k_dinv)
__global__ __launch_bounds__(256) void k_deg(const int* __restrict__ ei, long long E,
                                             const int* __restrict__ flag,
                                             float* __restrict__ deg) {
    long long e = (long long)blockIdx.x * 256 + threadIdx.x;
    if (e >= E) return;
    int is64 = *flag;
    int d = edge_at(ei, E + e, is64);
    atomicAdd(&deg[d], 1.0f);
}

__global__ __launch_bounds__(256) void k_dinv(float* __restrict__ dinv) {
    int i = blockIdx.x * 256 + threadIdx.x;
    if (i < N_NODES) dinv[i] = rsqrtf(dinv[i] + 1.0f);
}

// ---- h = relu(x @ W1 + b1)   [N,100]@[100,16]
__global__ __launch_bounds__(256) void k_lin1(const float* __restrict__ x,
                                              const float* __restrict__ W1,
                                              const float* __restrict__ b1,
                                              float* __restrict__ h) {
    __shared__ float sW[F_IN * HIDDEN];
    __shared__ float sb[HIDDEN];
    for (int i = threadIdx.x; i < F_IN * HIDDEN; i += 256) sW[i] = W1[i];
    if (threadIdx.x < HIDDEN) sb[threadIdx.x] = b1[threadIdx.x];
    __syncthreads();
    int node = blockIdx.x * 256 + threadIdx.x;
    if (node >= N_NODES) return;

    float acc[HIDDEN];
#pragma unroll
    for (int j = 0; j < HIDDEN; ++j) acc[j] = sb[j];

    const float4* x4 = reinterpret_cast<const float4*>(x + (long long)node * F_IN);
#pragma unroll 2
    for (int k4 = 0; k4 < F_IN / 4; ++k4) {
        float4 xv = x4[k4];
        const float* w = &sW[k4 * 4 * HIDDEN];
#pragma unroll
        for (int j = 0; j < HIDDEN; ++j) {
            acc[j] += xv.x * w[0 * HIDDEN + j];
            acc[j] += xv.y * w[1 * HIDDEN + j];
            acc[j] += xv.z * w[2 * HIDDEN + j];
            acc[j] += xv.w * w[3 * HIDDEN + j];
        }
    }
    float4* hr = reinterpret_cast<float4*>(h + (long long)node * HIDDEN);
#pragma unroll
    for (int q = 0; q < HIDDEN / 4; ++q) {
        float4 o;
        o.x = fmaxf(acc[q * 4 + 0], 0.0f);
        o.y = fmaxf(acc[q * 4 + 1], 0.0f);
        o.z = fmaxf(acc[q * 4 + 2], 0.0f);
        o.w = fmaxf(acc[q * 4 + 3], 0.0f);
        hr[q] = o;
    }
}

// ---- tmp' = dinv[i] * (h @ W);  agg init = tmp' (self-loop contribution)
__global__ __launch_bounds__(256) void k_mm16(const float* __restrict__ h,
                                              const float* __restrict__ W,
                                              const float* __restrict__ dinv,
                                              float* __restrict__ tmpp,
                                              float* __restrict__ agg) {
    __shared__ float sW[HIDDEN * HIDDEN];
    if (threadIdx.x < HIDDEN * HIDDEN) sW[threadIdx.x] = W[threadIdx.x];
    __syncthreads();
    int node = blockIdx.x * 256 + threadIdx.x;
    if (node >= N_NODES) return;

    float hv[HIDDEN];
    const float4* hr = reinterpret_cast<const float4*>(h + (long long)node * HIDDEN);
#pragma unroll
    for (int q = 0; q < HIDDEN / 4; ++q) {
        float4 v = hr[q];
        hv[q * 4 + 0] = v.x; hv[q * 4 + 1] = v.y;
        hv[q * 4 + 2] = v.z; hv[q * 4 + 3] = v.w;
    }
    float di = dinv[node];
    float out[HIDDEN];
#pragma unroll
    for (int j = 0; j < HIDDEN; ++j) out[j] = 0.0f;
#pragma unroll
    for (int k = 0; k < HIDDEN; ++k) {
        float hk = hv[k];
#pragma unroll
        for (int j = 0; j < HIDDEN; ++j) out[j] += hk * sW[k * HIDDEN + j];
    }
    float4* tp = reinterpret_cast<float4*>(tmpp + (long long)node * HIDDEN);
    float4* ap = reinterpret_cast<float4*>(agg + (long long)node * HIDDEN);
#pragma unroll
    for (int q = 0; q < HIDDEN / 4; ++q) {
        float4 o;
        o.x = di * out[q * 4 + 0];
        o.y = di * out[q * 4 + 1];
        o.z = di * out[q * 4 + 2];
        o.w = di * out[q * 4 + 3];
        tp[q] = o;
        ap[q] = o;
    }
}

// ---- scatter: agg[dst] += tmp'[src]; 16 lanes per edge (lane = feature)
__global__ __launch_bounds__(256) void k_scatter(const int* __restrict__ ei, long long E,
                                                 const int* __restrict__ flag,
                                                 const float* __restrict__ tmpp,
                                                 float* __restrict__ agg) {
    long long t = (long long)blockIdx.x * 256 + threadIdx.x;
    long long e = t >> 4;
    int f = (int)(t & 15);
    if (e >= E) return;
    int is64 = *flag;
    int s = edge_at(ei, e, is64);
    int d = edge_at(ei, E + e, is64);
    float v = tmpp[(long long)s * HIDDEN + f];
    atomicAdd(&agg[(long long)d * HIDDEN + f], v);
}

// ---- h = relu(dinv[i] * agg + b)
__global__ __launch_bounds__(256) void k_relu(const float* __restrict__ agg,
                                              const float* __restrict__ dinv,
                                              const float* __restrict__ b,
                                              float* __restrict__ h) {
    long long t = (long long)blockIdx.x * 256 + threadIdx.x;
    if (t >= (long long)N_NODES * HIDDEN) return;
    int node = (int)(t >> 4);
    int f = (int)(t & 15);
    h[t] = fmaxf(dinv[node] * agg[t] + b[f], 0.0f);
}

// ---- out = log_softmax(h @ W2 + b2)
__global__ __launch_bounds__(256) void k_out(const float* __restrict__ h,
                                             const float* __restrict__ W2,
                                             const float* __restrict__ b2,
                                             float* __restrict__ out) {
    __shared__ float sW[HIDDEN * N_CLASS];
    __shared__ float sb[N_CLASS];
    for (int i = threadIdx.x; i < HIDDEN * N_CLASS; i += 256) sW[i] = W2[i];
    if (threadIdx.x < N_CLASS) sb[threadIdx.x] = b2[threadIdx.x];
    __syncthreads();
    int node = blockIdx.x * 256 + threadIdx.x;
    if (node >= N_NODES) return;

    float hv[HIDDEN];
    const float4* hr = reinterpret_cast<const float4*>(h + (long long)node * HIDDEN);
#pragma unroll
    for (int q = 0; q < HIDDEN / 4; ++q) {
        float4 v = hr[q];
        hv[q * 4 + 0] = v.x; hv[q * 4 + 1] = v.y;
        hv[q * 4 + 2] = v.z; hv[q * 4 + 3] = v.w;
    }
    float z[N_CLASS];
#pragma unroll
    for (int c = 0; c < N_CLASS; ++c) z[c] = sb[c];
#pragma unroll
    for (int k = 0; k < HIDDEN; ++k) {
        float hk = hv[k];
#pragma unroll
        for (int c = 0; c < N_CLASS; ++c) z[c] += hk * sW[k * N_CLASS + c];
    }
    float m = z[0];
#pragma unroll
    for (int c = 1; c < N_CLASS; ++c) m = fmaxf(m, z[c]);
    float ssum = 0.0f;
#pragma unroll
    for (int c = 0; c < N_CLASS; ++c) ssum += expf(z[c] - m);
    float l = m + logf(ssum);
    float* orow = out + (long long)node * N_CLASS;
#pragma unroll
    for (int c = 0; c < N_CLASS; ++c) orow[c] = z[c] - l;
}

extern "C" void kernel_launch(void* const* d_in, const int* in_sizes, int n_in,
                              void* d_out, int out_size, void* d_ws, size_t ws_size,
                              hipStream_t stream) {
    const float* x   = (const float*)d_in[0];
    const int*   ei  = (const int*)d_in[1];
    const float* W1  = (const float*)d_in[2];
    const float* b1  = (const float*)d_in[3];
    const float* Wc0 = (const float*)d_in[4];
    const float* bc0 = (const float*)d_in[5];
    const float* Wc1 = (const float*)d_in[6];
    const float* bc1 = (const float*)d_in[7];
    const float* W2  = (const float*)d_in[8];
    const float* b2  = (const float*)d_in[9];
    float* out = (float*)d_out;

    long long E = (long long)in_sizes[1] / 2;

    char* ws = (char*)d_ws;
    int*   flag = (int*)ws;                                  // 256 B slot
    float* dinv = (float*)(ws + 256);                        // N floats
    float* h    = dinv + N_NODES;                            // N*16
    float* tmpp = h + (long long)N_NODES * HIDDEN;           // N*16
    float* agg  = tmpp + (long long)N_NODES * HIDDEN;        // N*16

    const int nblk_node   = (N_NODES + 255) / 256;
    const int nblk_edge   = (int)((E + 255) / 256);
    const int nblk_scat   = (int)((E * 16 + 255) / 256);
    const int nblk_nf     = (int)(((long long)N_NODES * HIDDEN + 255) / 256);

    hipMemsetAsync(dinv, 0, N_NODES * sizeof(float), stream);
    k_detect<<<1, 1, 0, stream>>>(ei, flag);
    k_deg<<<nblk_edge, 256, 0, stream>>>(ei, E, flag, dinv);
    k_dinv<<<nblk_node, 256, 0, stream>>>(dinv);

    k_lin1<<<nblk_node, 256, 0, stream>>>(x, W1, b1, h);

    // conv 1
    k_mm16<<<nblk_node, 256, 0, stream>>>(h, Wc0, dinv, tmpp, agg);
    k_scatter<<<nblk_scat, 256, 0, stream>>>(ei, E, flag, tmpp, agg);
    k_relu<<<nblk_nf, 256, 0, stream>>>(agg, dinv, bc0, h);

    // conv 2
    k_mm16<<<nblk_node, 256, 0, stream>>>(h, Wc1, dinv, tmpp, agg);
    k_scatter<<<nblk_scat, 256, 0, stream>>>(ei, E, flag, tmpp, agg);
    k_relu<<<nblk_nf, 256, 0, stream>>>(agg, dinv, bc1, h);

    k_out<<<nblk_node, 256, 0, stream>>>(h, W2, b2, out);
}